// Round 1
// 479.227 us; speedup vs baseline: 1.9967x; 1.9967x over previous
//
#include <hip/hip_runtime.h>
#include <hip/hip_bf16.h>
#include <stdint.h>

// CachedOPTAttention: B=4, T=1024, D=2048, H=32, HD=64, causal, idx=0.
// FP32 buffers; bf16-class error budget (0.10125) -> bf16 MFMA math inside.
//
// R3 plan: pre-convert operands to bf16 once, then run all four GEMMs with the
// proven m97 structure (128x128 tile, BK=32, global_load_lds width=16, 2-barrier
// K-loop). W is transposed+converted to bf16 (n-major, k-contiguous) so B-tile
// staging is linear and B-fragments are ds_read_b128.
//
// Buffer plan:
//   d_out: [0,16MB)  xb  = bf16(x)            (dead after V GEMM)
//          [16,32MB) qb  = bf16(x@Wq+bq)      (dead after attention)
//          [32,96MB) cache f32 (final output; K/V GEMMs write it directly)
//          O GEMM finally overwrites [0,32MB) with out f32.
//   d_ws:  [0,8MB)   WT  = bf16 W^T (sequentially reused per GEMM)
//          [8,24MB)  ctxb = bf16 attention output

typedef __hip_bfloat16 bf16;
typedef short s16x8 __attribute__((ext_vector_type(8)));
typedef float f32x4 __attribute__((ext_vector_type(4)));

#define T_SEQ   1024
#define D_MODEL 2048

__device__ inline unsigned short f2b(float f) {
    bf16 h = __float2bfloat16(f);
    return *(unsigned short*)&h;
}

typedef __attribute__((address_space(1))) const void gas_void;
typedef __attribute__((address_space(3))) void las_void;

__device__ inline void gl2lds16(const void* g, void* l) {
    // per-lane global src, wave-uniform LDS base + lane*16 dest
    __builtin_amdgcn_global_load_lds((gas_void*)g, (las_void*)l, 16, 0, 0);
}

// ---------------------------------------------------------------------------
// x[4096][2048] f32 -> bf16 (linear)
// ---------------------------------------------------------------------------
__global__ __launch_bounds__(256)
void cvtx_kernel(const float* __restrict__ x, unsigned short* __restrict__ xb)
{
    const size_t i = ((size_t)blockIdx.x * 256 + threadIdx.x) * 8;
    float4 a = *(const float4*)(x + i);
    float4 b = *(const float4*)(x + i + 4);
    union { uint4 u; unsigned short s[8]; } p;
    p.s[0] = f2b(a.x); p.s[1] = f2b(a.y); p.s[2] = f2b(a.z); p.s[3] = f2b(a.w);
    p.s[4] = f2b(b.x); p.s[5] = f2b(b.y); p.s[6] = f2b(b.z); p.s[7] = f2b(b.w);
    *(uint4*)(xb + i) = p.u;
}

// ---------------------------------------------------------------------------
// W[2048][2048] f32 (k-major) -> WT[2048][2048] bf16 (n-major, k contiguous).
// 64x64 tile via LDS (pad 65 -> 2-way max on both phases).
// ---------------------------------------------------------------------------
__global__ __launch_bounds__(256)
void wtrans_kernel(const float* __restrict__ W, unsigned short* __restrict__ Wt)
{
    __shared__ float tile[64][65];
    const int tid = threadIdx.x;
    const int k0 = blockIdx.y * 64, n0 = blockIdx.x * 64;

    const int rr = tid >> 4, cc = (tid & 15) * 4;
    #pragma unroll
    for (int i = 0; i < 4; ++i) {
        float4 v = *(const float4*)(W + (size_t)(k0 + rr + i * 16) * D_MODEL + n0 + cc);
        tile[rr + i * 16][cc]     = v.x;
        tile[rr + i * 16][cc + 1] = v.y;
        tile[rr + i * 16][cc + 2] = v.z;
        tile[rr + i * 16][cc + 3] = v.w;
    }
    __syncthreads();

    const int nr = tid >> 3, kc = (tid & 7) * 8;
    #pragma unroll
    for (int i = 0; i < 2; ++i) {
        const int n = nr + i * 32;
        union { uint4 u; unsigned short s[8]; } p;
        #pragma unroll
        for (int j = 0; j < 8; ++j) p.s[j] = f2b(tile[kc + j][n]);
        *(uint4*)(Wt + (size_t)(n0 + n) * D_MODEL + k0 + kc) = p.u;
    }
}

// ---------------------------------------------------------------------------
// GEMM (m97 structure): C[4096,2048] = A[4096,2048](bf16) @ WT^T + bias.
// WT is bf16 [N][K] (k contiguous). 128x128 tile, BK=32, 256 thr = 4 waves
// (2x2), each wave 64x64 = 4x4 16x16 frags. Staging: 16 global_load_lds
// dwordx4 per block per K-step (4 per wave), linear LDS [row][k].
// MODE: 0 = f32 linear out, 1 = f32 cache (row swizzle by slot/idx),
//       2 = bf16 linear out.
// ---------------------------------------------------------------------------
template<int MODE>
__global__ __launch_bounds__(256)
void gemm128_kernel(const unsigned short* __restrict__ A,
                    const unsigned short* __restrict__ Bt,
                    const float* __restrict__ bias,
                    float* __restrict__ out,
                    int slot, const int* __restrict__ idxp)
{
    __shared__ __align__(16) unsigned short As[128 * 32];
    __shared__ __align__(16) unsigned short Bs[128 * 32];

    const int tid  = threadIdx.x;
    const int wave = tid >> 6;
    const int lane = tid & 63;
    const int quad = lane >> 4;
    const int l15  = lane & 15;
    const int wm   = wave >> 1;
    const int wn   = wave & 1;
    const int m0   = blockIdx.y * 128;
    const int n0   = blockIdx.x * 128;

    // staging: wave stages chunks ca, ca+1 (16 rows x 32 k each = 1KB)
    const int ca   = wave * 2;
    const int rowc = lane >> 2;        // row within chunk
    const int kofs = (lane & 3) * 8;   // 8-elem k chunk (16B)

    const unsigned short* aG = A  + (size_t)(m0 + ca * 16 + rowc) * D_MODEL + kofs;
    const unsigned short* bG = Bt + (size_t)(n0 + ca * 16 + rowc) * D_MODEL + kofs;
    unsigned short* aL = As + ca * 512;
    unsigned short* bL = Bs + ca * 512;

    f32x4 acc[4][4];
    #pragma unroll
    for (int mi = 0; mi < 4; ++mi)
        #pragma unroll
        for (int ni = 0; ni < 4; ++ni) acc[mi][ni] = f32x4{0.f, 0.f, 0.f, 0.f};

    for (int k0 = 0; k0 < D_MODEL; k0 += 32) {
        gl2lds16(aG + k0,                aL);
        gl2lds16(aG + k0 + 16 * D_MODEL, aL + 512);
        gl2lds16(bG + k0,                bL);
        gl2lds16(bG + k0 + 16 * D_MODEL, bL + 512);
        __syncthreads();   // vmcnt(0) drain -> staged data visible

        s16x8 af[4], bfr[4];
        #pragma unroll
        for (int mi = 0; mi < 4; ++mi)
            af[mi] = *(const s16x8*)(As + (wm * 64 + mi * 16 + l15) * 32 + quad * 8);
        #pragma unroll
        for (int ni = 0; ni < 4; ++ni)
            bfr[ni] = *(const s16x8*)(Bs + (wn * 64 + ni * 16 + l15) * 32 + quad * 8);
        #pragma unroll
        for (int mi = 0; mi < 4; ++mi)
            #pragma unroll
            for (int ni = 0; ni < 4; ++ni)
                acc[mi][ni] = __builtin_amdgcn_mfma_f32_16x16x32_bf16(af[mi], bfr[ni], acc[mi][ni], 0, 0, 0);
        __syncthreads();   // all frag reads done before restage
    }

    const int idx = (MODE == 1) ? idxp[0] : 0;
    #pragma unroll
    for (int ni = 0; ni < 4; ++ni) {
        const int col = n0 + wn * 64 + ni * 16 + l15;
        const float bv = bias[col];
        #pragma unroll
        for (int mi = 0; mi < 4; ++mi) {
            #pragma unroll
            for (int r = 0; r < 4; ++r) {
                const int m = m0 + wm * 64 + mi * 16 + quad * 4 + r;
                const float v = acc[mi][ni][r] + bv;
                if (MODE == 0) {
                    out[(size_t)m * D_MODEL + col] = v;
                } else if (MODE == 1) {
                    const int b  = m >> 10;
                    const int tt = ((m & 1023) + idx) & 1023;
                    out[((size_t)(b * 2 + slot) * T_SEQ + tt) * D_MODEL + col] = v;
                } else {
                    ((unsigned short*)out)[(size_t)m * D_MODEL + col] = f2b(v);
                }
            }
        }
    }
}

// ---------------------------------------------------------------------------
// MFMA flash attention (unchanged structure from R2). Changes this round:
// q input is bf16 (direct LDS copy, no convert); 1/sqrt(64) scale applied to
// S after the QK^T MFMA (exact pow2); ctx written as bf16 for the O GEMM.
// ---------------------------------------------------------------------------
#define LDW 72

__global__ __launch_bounds__(256)
void attn_mfma_kernel(const unsigned short* __restrict__ q,
                      const float* __restrict__ cache,
                      unsigned short* __restrict__ ctx)
{
    __shared__ __align__(16) unsigned short Qs[64 * LDW];  // Qs[q][d]
    __shared__ __align__(16) unsigned short Ks[64 * LDW];  // Ks[key][d]
    __shared__ __align__(16) unsigned short Vt[64 * LDW];  // Vt[d][key]
    __shared__ __align__(16) unsigned short Ps[64 * LDW];  // Ps[q][key]

    const int tid  = threadIdx.x;
    const int wave = tid >> 6;
    const int lane = tid & 63;
    const int quad = lane >> 4;
    const int l15  = lane & 15;

    const int bh = blockIdx.x;          // b*32 + h
    const int b  = bh >> 5;
    const int h  = bh & 31;
    const int qt = 15 - blockIdx.y;     // query tile 0..15

    const int srow = tid >> 2;          // staging row 0..63
    const int part = tid & 3;           // staging 16-dim chunk

    const float* kbase = cache + ((size_t)(b * 2 + 0) * T_SEQ) * D_MODEL + h * 64;
    const float* vbase = cache + ((size_t)(b * 2 + 1) * T_SEQ) * D_MODEL + h * 64;

    // ---- stage Q tile (bf16 -> bf16 copy) ----
    {
        const uint4* qg = (const uint4*)(q + (size_t)(b * T_SEQ + qt * 64 + srow) * D_MODEL
                                           + h * 64 + part * 16);
        uint4 q0 = qg[0], q1 = qg[1];
        *(uint4*)(Qs + srow * LDW + part * 16)     = q0;
        *(uint4*)(Qs + srow * LDW + part * 16 + 8) = q1;
    }
    __syncthreads();

    const s16x8 qf0 = *(const s16x8*)(Qs + (wave * 16 + l15) * LDW + quad * 8);
    const s16x8 qf1 = *(const s16x8*)(Qs + (wave * 16 + l15) * LDW + 32 + quad * 8);

    f32x4 oacc[4];
    #pragma unroll
    for (int t = 0; t < 4; ++t) oacc[t] = f32x4{0.f, 0.f, 0.f, 0.f};
    float m_run[4] = {-1e30f, -1e30f, -1e30f, -1e30f};
    float l_run[4] = {0.f, 0.f, 0.f, 0.f};

    for (int kt = 0; kt <= qt; ++kt) {
        __syncthreads();   // prior tile's frag reads done; safe to restage

        {
            const float4* kg = (const float4*)(kbase + (size_t)(kt * 64 + srow) * D_MODEL + part * 16);
            const float4* vg = (const float4*)(vbase + (size_t)(kt * 64 + srow) * D_MODEL + part * 16);
            float4 k0 = kg[0], k1 = kg[1], k2 = kg[2], k3 = kg[3];
            float4 v0 = vg[0], v1 = vg[1], v2 = vg[2], v3 = vg[3];
            float kv[16] = {k0.x, k0.y, k0.z, k0.w, k1.x, k1.y, k1.z, k1.w,
                            k2.x, k2.y, k2.z, k2.w, k3.x, k3.y, k3.z, k3.w};
            float vv[16] = {v0.x, v0.y, v0.z, v0.w, v1.x, v1.y, v1.z, v1.w,
                            v2.x, v2.y, v2.z, v2.w, v3.x, v3.y, v3.z, v3.w};
            union { uint4 u; unsigned short s[8]; } p0, p1;
            #pragma unroll
            for (int i = 0; i < 8; ++i) { p0.s[i] = f2b(kv[i]); p1.s[i] = f2b(kv[8 + i]); }
            *(uint4*)(Ks + srow * LDW + part * 16)     = p0.u;
            *(uint4*)(Ks + srow * LDW + part * 16 + 8) = p1.u;
            #pragma unroll
            for (int j = 0; j < 16; ++j) Vt[(part * 16 + j) * LDW + srow] = f2b(vv[j]);
        }
        __syncthreads();

        // ---- S = Q @ K^T ----
        f32x4 sacc[4];
        #pragma unroll
        for (int t = 0; t < 4; ++t) sacc[t] = f32x4{0.f, 0.f, 0.f, 0.f};
        #pragma unroll
        for (int t = 0; t < 4; ++t) {
            s16x8 kf0 = *(const s16x8*)(Ks + (t * 16 + l15) * LDW + quad * 8);
            s16x8 kf1 = *(const s16x8*)(Ks + (t * 16 + l15) * LDW + 32 + quad * 8);
            sacc[t] = __builtin_amdgcn_mfma_f32_16x16x32_bf16(qf0, kf0, sacc[t], 0, 0, 0);
            sacc[t] = __builtin_amdgcn_mfma_f32_16x16x32_bf16(qf1, kf1, sacc[t], 0, 0, 0);
        }
        // scale 1/sqrt(64) (exact pow2), folded here instead of Q staging
        #pragma unroll
        for (int t = 0; t < 4; ++t)
            #pragma unroll
            for (int r = 0; r < 4; ++r) sacc[t][r] *= 0.125f;

        if (kt == qt) {
            #pragma unroll
            for (int t = 0; t < 4; ++t) {
                const int keyl = t * 16 + l15;
                #pragma unroll
                for (int r = 0; r < 4; ++r) {
                    if (keyl > wave * 16 + quad * 4 + r) sacc[t][r] = -1e30f;
                }
            }
        }

        // ---- online softmax ----
        float rmax[4];
        #pragma unroll
        for (int r = 0; r < 4; ++r)
            rmax[r] = fmaxf(fmaxf(sacc[0][r], sacc[1][r]), fmaxf(sacc[2][r], sacc[3][r]));
        #pragma unroll
        for (int off = 1; off < 16; off <<= 1) {
            #pragma unroll
            for (int r = 0; r < 4; ++r) rmax[r] = fmaxf(rmax[r], __shfl_xor(rmax[r], off, 16));
        }
        float alpha[4];
        #pragma unroll
        for (int r = 0; r < 4; ++r) {
            const float mnew = fmaxf(m_run[r], rmax[r]);
            alpha[r] = __expf(m_run[r] - mnew);
            m_run[r] = mnew;
        }
        float rsum[4] = {0.f, 0.f, 0.f, 0.f};
        #pragma unroll
        for (int t = 0; t < 4; ++t) {
            #pragma unroll
            for (int r = 0; r < 4; ++r) {
                const float p = __expf(sacc[t][r] - m_run[r]);
                sacc[t][r] = p;
                rsum[r] += p;
            }
        }
        #pragma unroll
        for (int off = 1; off < 16; off <<= 1) {
            #pragma unroll
            for (int r = 0; r < 4; ++r) rsum[r] += __shfl_xor(rsum[r], off, 16);
        }
        #pragma unroll
        for (int r = 0; r < 4; ++r) l_run[r] = l_run[r] * alpha[r] + rsum[r];
        #pragma unroll
        for (int t = 0; t < 4; ++t) {
            #pragma unroll
            for (int r = 0; r < 4; ++r) oacc[t][r] *= alpha[r];
        }

        #pragma unroll
        for (int t = 0; t < 4; ++t) {
            #pragma unroll
            for (int r = 0; r < 4; ++r)
                Ps[(wave * 16 + quad * 4 + r) * LDW + t * 16 + l15] = f2b(sacc[t][r]);
        }

        s16x8 pf0 = *(const s16x8*)(Ps + (wave * 16 + l15) * LDW + quad * 8);
        s16x8 pf1 = *(const s16x8*)(Ps + (wave * 16 + l15) * LDW + 32 + quad * 8);
        #pragma unroll
        for (int t = 0; t < 4; ++t) {
            s16x8 vf0 = *(const s16x8*)(Vt + (t * 16 + l15) * LDW + quad * 8);
            s16x8 vf1 = *(const s16x8*)(Vt + (t * 16 + l15) * LDW + 32 + quad * 8);
            oacc[t] = __builtin_amdgcn_mfma_f32_16x16x32_bf16(pf0, vf0, oacc[t], 0, 0, 0);
            oacc[t] = __builtin_amdgcn_mfma_f32_16x16x32_bf16(pf1, vf1, oacc[t], 0, 0, 0);
        }
    }

    // ---- epilogue: ctx (bf16) = O / l ----
    float invl[4];
    #pragma unroll
    for (int r = 0; r < 4; ++r) invl[r] = 1.0f / l_run[r];
    #pragma unroll
    for (int r = 0; r < 4; ++r) {
        const int qrow = qt * 64 + wave * 16 + quad * 4 + r;
        unsigned short* orow = ctx + (size_t)(b * T_SEQ + qrow) * D_MODEL + h * 64;
        #pragma unroll
        for (int t = 0; t < 4; ++t) orow[t * 16 + l15] = f2b(oacc[t][r] * invl[r]);
    }
}

// ---------------------------------------------------------------------------
extern "C" void kernel_launch(void* const* d_in, const int* in_sizes, int n_in,
                              void* d_out, int out_size, void* d_ws, size_t ws_size,
                              hipStream_t stream)
{
    const float* x    = (const float*)d_in[0];
    const int*   idxp = (const int*)d_in[3];
    const float* Wq   = (const float*)d_in[4];
    const float* bq   = (const float*)d_in[5];
    const float* Wk   = (const float*)d_in[6];
    const float* bk   = (const float*)d_in[7];
    const float* Wv   = (const float*)d_in[8];
    const float* bv   = (const float*)d_in[9];
    const float* Wo   = (const float*)d_in[10];
    const float* bo   = (const float*)d_in[11];

    float* out = (float*)d_out;
    unsigned short* xb = (unsigned short*)d_out;                              // [0,16MB)
    unsigned short* qb = (unsigned short*)d_out + (size_t)8 * 1024 * 1024;    // [16,32MB)
    float* cacheOut    = out + (size_t)4 * T_SEQ * D_MODEL;                   // [32,96MB)

    unsigned short* WT   = (unsigned short*)d_ws;                             // 8MB
    unsigned short* ctxb = (unsigned short*)d_ws + (size_t)4 * 1024 * 1024;   // 16MB

    const dim3 tb(256);
    const dim3 tg(32, 32);   // wtrans: 64x64 tiles over 2048x2048
    const dim3 gg(16, 32);   // gemm: N/128 x M/128

    cvtx_kernel<<<dim3(4096), tb, 0, stream>>>(x, xb);

    wtrans_kernel<<<tg, tb, 0, stream>>>(Wq, WT);
    gemm128_kernel<2><<<gg, tb, 0, stream>>>(xb, WT, bq, (float*)qb, 0, nullptr);

    wtrans_kernel<<<tg, tb, 0, stream>>>(Wk, WT);
    gemm128_kernel<1><<<gg, tb, 0, stream>>>(xb, WT, bk, cacheOut, 0, idxp);

    wtrans_kernel<<<tg, tb, 0, stream>>>(Wv, WT);
    gemm128_kernel<1><<<gg, tb, 0, stream>>>(xb, WT, bv, cacheOut, 1, idxp);

    attn_mfma_kernel<<<dim3(128, 16), tb, 0, stream>>>(qb, cacheOut, ctxb);

    wtrans_kernel<<<tg, tb, 0, stream>>>(Wo, WT);
    gemm128_kernel<0><<<gg, tb, 0, stream>>>(ctxb, WT, bo, out, 0, nullptr);
}